// Round 4
// baseline (88.359 us; speedup 1.0000x reference)
//
#include <hip/hip_runtime.h>
#include <hip/hip_bf16.h>

// InfoNCE-style loss: Xn=normalize(X), Yn=normalize(Y), logits=Xn@Yn^T/0.07,
// loss = mean_i(lse_i - logits[i,i]).
// Fixed-max trick: logits <= 1/T, so lse = 1/T + ln(sum_j exp(logit-1/T)).
//
// ws layout:
//   [0,4MB)        Xn bf16 [8192][256]
//   [4MB,8MB)      Yn bf16 [8192][256]
//   [8MB,+32KB)    diag f32[8192]
//   [8MB+32K,+32K) row_sum f32[8192]  (zeroed by nrm_kernel each call)

typedef __attribute__((ext_vector_type(4)))  float f32x4;
typedef __attribute__((ext_vector_type(16))) float f32x16;
typedef __attribute__((ext_vector_type(8)))  short s16x8;

#define AS1(p) ((const __attribute__((address_space(1))) void*)(uintptr_t)(p))
#define AS3(p) ((__attribute__((address_space(3))) void*)(uintptr_t)(p))

constexpr int   BROWS = 8192;
constexpr int   DDIM  = 256;
constexpr float kInvT = 14.285714285714286f;   // 1/0.07
constexpr float kC1   = 20.609929155556622f;   // log2(e)/0.07
constexpr float kLn2  = 0.6931471805599453f;

#if __has_builtin(__builtin_amdgcn_exp2f)
#define EXP2F(x) __builtin_amdgcn_exp2f(x)
#else
#define EXP2F(x) exp2f(x)
#endif
#if __has_builtin(__builtin_amdgcn_logf)
#define LOG2F(x) __builtin_amdgcn_logf(x)
#else
#define LOG2F(x) log2f(x)
#endif

static __device__ __forceinline__ unsigned short f2bf(float f) {
  unsigned u = __builtin_bit_cast(unsigned, f);
  unsigned rounding = 0x7FFFu + ((u >> 16) & 1u);
  return (unsigned short)((u + rounding) >> 16);
}

// ---------------- normalize rows + exact fp32 diagonal + zero row_sum ------
__global__ __launch_bounds__(256) void nrm_kernel(
    const float* __restrict__ X, const float* __restrict__ Y,
    unsigned short* __restrict__ Xn, unsigned short* __restrict__ Yn,
    float* __restrict__ diag, float* __restrict__ row_sum)
{
  const int wave = threadIdx.x >> 6;
  const int lane = threadIdx.x & 63;
  const int row  = blockIdx.x * 4 + wave;
  const float4 x = *(const float4*)(X + (size_t)row * DDIM + lane * 4);
  const float4 y = *(const float4*)(Y + (size_t)row * DDIM + lane * 4);
  float ssx = x.x*x.x + x.y*x.y + x.z*x.z + x.w*x.w;
  float ssy = y.x*y.x + y.y*y.y + y.z*y.z + y.w*y.w;
  float dot = x.x*y.x + x.y*y.y + x.z*y.z + x.w*y.w;
  #pragma unroll
  for (int m = 1; m < 64; m <<= 1) {
    ssx += __shfl_xor(ssx, m);
    ssy += __shfl_xor(ssy, m);
    dot += __shfl_xor(dot, m);
  }
  const float invx = 1.0f / fmaxf(sqrtf(ssx), 1e-8f);
  const float invy = 1.0f / fmaxf(sqrtf(ssy), 1e-8f);
  ushort4 ox, oy;
  ox.x = f2bf(x.x * invx); ox.y = f2bf(x.y * invx);
  ox.z = f2bf(x.z * invx); ox.w = f2bf(x.w * invx);
  oy.x = f2bf(y.x * invy); oy.y = f2bf(y.y * invy);
  oy.z = f2bf(y.z * invy); oy.w = f2bf(y.w * invy);
  *(ushort4*)(Xn + (size_t)row * DDIM + lane * 4) = ox;
  *(ushort4*)(Yn + (size_t)row * DDIM + lane * 4) = oy;
  if (lane == 0) {
    diag[row] = dot * invx * invy * kInvT;
    row_sum[row] = 0.0f;
  }
}

// -------- one B-tile: 32 MFMAs (32x32x16) + interleaved exp of PREV tile ---
// Per ks-step: 1 ds_read_b128 (XOR-static addr), 2 MFMA, 2 exps of prev.
// prev elements are re-zeroed as consumed so `prev` is ready to be `cur`.
__device__ __forceinline__ void tile_mfma(
    const char* __restrict__ bb, int addr0, const s16x8 (&a)[2][16],
    f32x16 (&cur)[2], f32x16 (&prev)[2], float (&sums)[2][16])
{
  __builtin_amdgcn_s_setprio(1);
  #pragma unroll
  for (int ks = 0; ks < 16; ++ks) {
    const s16x8 b = *(const s16x8*)(bb + (addr0 ^ (ks << 5)));
    cur[0] = __builtin_amdgcn_mfma_f32_32x32x16_bf16(a[0][ks], b, cur[0], 0, 0, 0);
    cur[1] = __builtin_amdgcn_mfma_f32_32x32x16_bf16(a[1][ks], b, cur[1], 0, 0, 0);
    constexpr int two = 2;
    const int i0 = two * ks, i1 = two * ks + 1;
    sums[i0 >> 4][i0 & 15] += EXP2F(__builtin_fmaf(prev[i0 >> 4][i0 & 15], kC1, -kC1));
    sums[i1 >> 4][i1 & 15] += EXP2F(__builtin_fmaf(prev[i1 >> 4][i1 & 15], kC1, -kC1));
    prev[i0 >> 4][i0 & 15] = 0.0f;
    prev[i1 >> 4][i1 & 15] = 0.0f;
  }
  __builtin_amdgcn_s_setprio(0);
}

// ---------------- main: exp-sum of logits over all columns ----------------
// 512 blocks x 256 thr (4 waves). Wave owns 64 X-rows as 2 m-frags of 32,
// A in registers (128 VGPR). B tile = 32 Y-rows x 256 (16KB), 4-deep LDS
// ring via global_load_lds (linear dest + pre-swizzled src, (row&15)<<4).
// One vmcnt(0)+s_barrier per TWO tiles; outer loop unrolled x4 so LDS
// buffer bases are compile-time immediates. T15 acc double-buffer overlaps
// each tile's exp epilogue with the next tile's MFMA stream.
__global__ __launch_bounds__(256, 2) void logits_kernel(
    const unsigned short* __restrict__ Xn,
    const unsigned short* __restrict__ Yn,
    float* __restrict__ row_sum)
{
  __shared__ char lds[4 * 16384];
  const int tid  = threadIdx.x;
  const int lane = tid & 63;
  const int wave = tid >> 6;
  const int l31  = lane & 31;
  const int lhi  = lane >> 5;      // 0,1: k-chunk selector

  // XCD-aware bijective map: xcd=bid&7 owns 16 panels x 4 splits (~3MB/L2)
  const int bid  = blockIdx.x;
  const int xcd  = bid & 7;
  const int idx  = bid >> 3;                        // 0..63
  const int panel = (xcd >> 2) * 16 + (idx & 15);   // 0..31
  const int split = (xcd & 3) * 4 + (idx >> 4);     // 0..15

  const int rowbase = panel * 256 + wave * 64;
  const char* Xb = (const char*)Xn;
  const char* Yb = (const char*)Yn + (size_t)split * (512 * 512);

  // A fragments (32x32x16): lane holds row (rowbase+32m+l31),
  // k = 16*ks + 8*lhi .. +8  -> 16B at byte offset 32*ks + 16*lhi.
  s16x8 a[2][16];
  #pragma unroll
  for (int m = 0; m < 2; ++m) {
    const char* rp = Xb + (size_t)(rowbase + m * 32 + l31) * 512 + lhi * 16;
    #pragma unroll
    for (int ks = 0; ks < 16; ++ks)
      a[m][ks] = *(const s16x8*)(rp + ks * 32);
  }

  float sums[2][16];
  #pragma unroll
  for (int m = 0; m < 2; ++m)
    #pragma unroll
    for (int g = 0; g < 16; ++g) sums[m][g] = 0.0f;

  // B read base: lane reads Y-row r=l31 bytes c0 = 32*ks + 16*lhi,
  // swizzled addr = r*512 + (c0 ^ ((r&15)<<4)) = addr0 ^ (ks<<5).
  const int addr0 = l31 * 512 + ((lhi * 16) ^ ((lane & 15) << 4));

  auto stage = [&](int t, int b) {
    const char* Yt = Yb + (size_t)t * 16384;
    char* db = lds + b * 16384;
    #pragma unroll
    for (int s = 0; s < 4; ++s) {
      const int portion = (s * 4 + wave) * 1024;
      const int L = portion + lane * 16;
      const int src = L ^ (((L >> 9) & 15) << 4);
      __builtin_amdgcn_global_load_lds(AS1(Yt + src), AS3(db + portion), 16, 0, 0);
    }
  };

  // acc double-buffer: accA = cur of even tiles, accB = cur of odd tiles.
  // accB starts at -inf so tile 0's "prev" exp contributes exactly 0.
  f32x16 accA[2], accB[2];
  #pragma unroll
  for (int m = 0; m < 2; ++m)
    #pragma unroll
    for (int r = 0; r < 16; ++r) {
      accA[m][r] = 0.0f;
      accB[m][r] = -__builtin_inff();
    }

  stage(0, 0);
  stage(1, 1);
  #pragma unroll 1
  for (int q = 0; q < 4; ++q) {
    const int j = 4 * q;
    // pair A: tiles j, j+1 (bufs 0,1); stage j+2 -> buf2, j+3 -> buf3
    asm volatile("s_waitcnt vmcnt(0)" ::: "memory");
    __builtin_amdgcn_s_barrier();
    stage(j + 2, 2);
    tile_mfma(lds + 0 * 16384, addr0, a, accA, accB, sums);
    stage(j + 3, 3);
    tile_mfma(lds + 1 * 16384, addr0, a, accB, accA, sums);
    // pair B: tiles j+2, j+3 (bufs 2,3); stage j+4 -> buf0, j+5 -> buf1
    asm volatile("s_waitcnt vmcnt(0)" ::: "memory");
    __builtin_amdgcn_s_barrier();
    if (q < 3) stage(j + 4, 0);
    tile_mfma(lds + 2 * 16384, addr0, a, accA, accB, sums);
    if (q < 3) stage(j + 5, 1);
    tile_mfma(lds + 3 * 16384, addr0, a, accB, accA, sums);
  }
  // flush tile 15 (its results live in accB)
  #pragma unroll
  for (int m = 0; m < 2; ++m)
    #pragma unroll
    for (int r = 0; r < 16; ++r)
      sums[m][r] += EXP2F(__builtin_fmaf(accB[m][r], kC1, -kC1));

  // reduce across the 32 column-lanes; one atomic per row per split.
  // C/D row mapping: row = (g&3) + 8*(g>>2) + 4*lhi, col = l31.
  #pragma unroll
  for (int m = 0; m < 2; ++m)
    #pragma unroll
    for (int g = 0; g < 16; ++g) {
      float s = sums[m][g];
      s += __shfl_xor(s, 1);
      s += __shfl_xor(s, 2);
      s += __shfl_xor(s, 4);
      s += __shfl_xor(s, 8);
      s += __shfl_xor(s, 16);
      if (l31 == 0)
        atomicAdd(row_sum + rowbase + m * 32 + (g & 3) + 8 * (g >> 2) + 4 * lhi, s);
    }
}

// ---------------- loss: single-kernel reduction ----------------
__global__ __launch_bounds__(1024) void loss_kernel(
    const float* __restrict__ row_sum, const float* __restrict__ diag,
    float* __restrict__ out)
{
  const int t = threadIdx.x;
  double acc = 0.0;
  #pragma unroll
  for (int h = 0; h < 2; ++h) {
    const int i = h * 4096 + t * 4;
    const float4 s = *(const float4*)(row_sum + i);
    const float4 d = *(const float4*)(diag + i);
    acc += (double)(kInvT + LOG2F(s.x) * kLn2 - d.x);
    acc += (double)(kInvT + LOG2F(s.y) * kLn2 - d.y);
    acc += (double)(kInvT + LOG2F(s.z) * kLn2 - d.z);
    acc += (double)(kInvT + LOG2F(s.w) * kLn2 - d.w);
  }
  #pragma unroll
  for (int m = 1; m < 64; m <<= 1) acc += __shfl_xor(acc, m);
  __shared__ double red[16];
  if ((t & 63) == 0) red[t >> 6] = acc;
  __syncthreads();
  if (t == 0) {
    double tot = 0.0;
    #pragma unroll
    for (int w = 0; w < 16; ++w) tot += red[w];
    out[0] = (float)(tot / (double)BROWS);
  }
}

extern "C" void kernel_launch(void* const* d_in, const int* in_sizes, int n_in,
                              void* d_out, int out_size, void* d_ws, size_t ws_size,
                              hipStream_t stream) {
  (void)in_sizes; (void)n_in; (void)out_size; (void)ws_size;
  const float* X = (const float*)d_in[0];
  const float* Y = (const float*)d_in[1];
  char* w = (char*)d_ws;
  unsigned short* Xn = (unsigned short*)(w);
  unsigned short* Yn = (unsigned short*)(w + (4u << 20));
  float* diag    = (float*)(w + (8u << 20));
  float* row_sum = (float*)(w + (8u << 20) + (32u << 10));

  nrm_kernel<<<BROWS / 4, 256, 0, stream>>>(X, Y, Xn, Yn, diag, row_sum);
  logits_kernel<<<512, 256, 0, stream>>>(Xn, Yn, row_sum);
  loss_kernel<<<1, 1024, 0, stream>>>(row_sum, diag, (float*)d_out);
}

// Round 5
// 73.732 us; speedup vs baseline: 1.1984x; 1.1984x over previous
//
#include <hip/hip_runtime.h>
#include <hip/hip_bf16.h>

// InfoNCE-style loss: Xn=normalize(X), Yn=normalize(Y), logits=Xn@Yn^T/0.07,
// loss = mean_i(lse_i - logits[i,i]).
// Fixed-max trick: logits <= 1/T, so lse = 1/T + ln(sum_j exp(logit-1/T)).
//
// ws layout:
//   [0,4MB)        Xn bf16 [8192][256]
//   [4MB,8MB)      Yn bf16 [8192][256]
//   [8MB,+32KB)    diag f32[8192]
//   [8MB+32K,+32K) row_sum f32[8192]  (zeroed by nrm_kernel each call)

typedef __attribute__((ext_vector_type(4)))  float f32x4;
typedef __attribute__((ext_vector_type(16))) float f32x16;
typedef __attribute__((ext_vector_type(8)))  short s16x8;

#define AS1(p) ((const __attribute__((address_space(1))) void*)(uintptr_t)(p))
#define AS3(p) ((__attribute__((address_space(3))) void*)(uintptr_t)(p))

constexpr int   BROWS = 8192;
constexpr int   DDIM  = 256;
constexpr float kInvT = 14.285714285714286f;   // 1/0.07
constexpr float kC1   = 20.609929155556622f;   // log2(e)/0.07
constexpr float kLn2  = 0.6931471805599453f;

#if __has_builtin(__builtin_amdgcn_exp2f)
#define EXP2F(x) __builtin_amdgcn_exp2f(x)
#else
#define EXP2F(x) exp2f(x)
#endif
#if __has_builtin(__builtin_amdgcn_logf)
#define LOG2F(x) __builtin_amdgcn_logf(x)
#else
#define LOG2F(x) log2f(x)
#endif

static __device__ __forceinline__ unsigned short f2bf(float f) {
  unsigned u = __builtin_bit_cast(unsigned, f);
  unsigned rounding = 0x7FFFu + ((u >> 16) & 1u);
  return (unsigned short)((u + rounding) >> 16);
}

// ---------------- normalize rows + exact fp32 diagonal + zero row_sum ------
__global__ __launch_bounds__(256) void nrm_kernel(
    const float* __restrict__ X, const float* __restrict__ Y,
    unsigned short* __restrict__ Xn, unsigned short* __restrict__ Yn,
    float* __restrict__ diag, float* __restrict__ row_sum)
{
  const int wave = threadIdx.x >> 6;
  const int lane = threadIdx.x & 63;
  const int row  = blockIdx.x * 4 + wave;
  const float4 x = *(const float4*)(X + (size_t)row * DDIM + lane * 4);
  const float4 y = *(const float4*)(Y + (size_t)row * DDIM + lane * 4);
  float ssx = x.x*x.x + x.y*x.y + x.z*x.z + x.w*x.w;
  float ssy = y.x*y.x + y.y*y.y + y.z*y.z + y.w*y.w;
  float dot = x.x*y.x + x.y*y.y + x.z*y.z + x.w*y.w;
  #pragma unroll
  for (int m = 1; m < 64; m <<= 1) {
    ssx += __shfl_xor(ssx, m);
    ssy += __shfl_xor(ssy, m);
    dot += __shfl_xor(dot, m);
  }
  const float invx = 1.0f / fmaxf(sqrtf(ssx), 1e-8f);
  const float invy = 1.0f / fmaxf(sqrtf(ssy), 1e-8f);
  ushort4 ox, oy;
  ox.x = f2bf(x.x * invx); ox.y = f2bf(x.y * invx);
  ox.z = f2bf(x.z * invx); ox.w = f2bf(x.w * invx);
  oy.x = f2bf(y.x * invy); oy.y = f2bf(y.y * invy);
  oy.z = f2bf(y.z * invy); oy.w = f2bf(y.w * invy);
  *(ushort4*)(Xn + (size_t)row * DDIM + lane * 4) = ox;
  *(ushort4*)(Yn + (size_t)row * DDIM + lane * 4) = oy;
  if (lane == 0) {
    diag[row] = dot * invx * invy * kInvT;
    row_sum[row] = 0.0f;
  }
}

// -------- one B-tile: 32 MFMAs (32x32x16) then exp epilogue ---------------
// Epilogue overlap comes from the co-resident wave of the OTHER block on
// each SIMD (2 blocks/CU, independent barrier phases), not from a second
// accumulator copy (which spilled in R4: 240+ regs -> 85MB scratch writes).
__device__ __forceinline__ void tile_mfma(
    const char* __restrict__ bb, int addr0, const s16x8 (&a)[2][16],
    f32x16 (&acc)[2], float (&sums)[2][16])
{
  __builtin_amdgcn_s_setprio(1);
  #pragma unroll
  for (int ks = 0; ks < 16; ++ks) {
    const s16x8 b = *(const s16x8*)(bb + (addr0 ^ (ks << 5)));
    acc[0] = __builtin_amdgcn_mfma_f32_32x32x16_bf16(a[0][ks], b, acc[0], 0, 0, 0);
    acc[1] = __builtin_amdgcn_mfma_f32_32x32x16_bf16(a[1][ks], b, acc[1], 0, 0, 0);
  }
  __builtin_amdgcn_s_setprio(0);
  #pragma unroll
  for (int m = 0; m < 2; ++m)
    #pragma unroll
    for (int r = 0; r < 16; ++r) {
      sums[m][r] += EXP2F(__builtin_fmaf(acc[m][r], kC1, -kC1));
      acc[m][r] = 0.0f;
    }
}

// ---------------- main: exp-sum of logits over all columns ----------------
// 512 blocks x 256 thr (4 waves). Wave owns 64 X-rows as 2 m-frags of 32,
// A in registers (128 regs). B tile = 32 Y-rows x 256 (16KB), 4-deep LDS
// ring via global_load_lds (linear dest + pre-swizzled src, (row&15)<<4 —
// 0 bank conflicts measured). One vmcnt(0)+s_barrier per TWO tiles; outer
// loop unrolled x4 so LDS buffer bases are compile-time immediates.
__global__ __launch_bounds__(256, 2) void logits_kernel(
    const unsigned short* __restrict__ Xn,
    const unsigned short* __restrict__ Yn,
    float* __restrict__ row_sum)
{
  __shared__ char lds[4 * 16384];
  const int tid  = threadIdx.x;
  const int lane = tid & 63;
  const int wave = tid >> 6;
  const int l31  = lane & 31;
  const int lhi  = lane >> 5;      // 0,1: k-chunk selector

  // XCD-aware bijective map: xcd=bid&7 owns 16 panels x 4 splits (~3MB/L2)
  const int bid  = blockIdx.x;
  const int xcd  = bid & 7;
  const int idx  = bid >> 3;                        // 0..63
  const int panel = (xcd >> 2) * 16 + (idx & 15);   // 0..31
  const int split = (xcd & 3) * 4 + (idx >> 4);     // 0..15

  const int rowbase = panel * 256 + wave * 64;
  const char* Xb = (const char*)Xn;
  const char* Yb = (const char*)Yn + (size_t)split * (512 * 512);

  // A fragments (32x32x16): lane holds row (rowbase+32m+l31),
  // k = 16*ks + 8*lhi .. +8  -> 16B at byte offset 32*ks + 16*lhi.
  s16x8 a[2][16];
  #pragma unroll
  for (int m = 0; m < 2; ++m) {
    const char* rp = Xb + (size_t)(rowbase + m * 32 + l31) * 512 + lhi * 16;
    #pragma unroll
    for (int ks = 0; ks < 16; ++ks)
      a[m][ks] = *(const s16x8*)(rp + ks * 32);
  }

  float sums[2][16];
  #pragma unroll
  for (int m = 0; m < 2; ++m)
    #pragma unroll
    for (int g = 0; g < 16; ++g) sums[m][g] = 0.0f;

  // B read base: lane reads Y-row r=l31 bytes c0 = 32*ks + 16*lhi,
  // swizzled addr = r*512 + (c0 ^ ((r&15)<<4)) = addr0 ^ (ks<<5).
  const int addr0 = l31 * 512 + ((lhi * 16) ^ ((lane & 15) << 4));

  auto stage = [&](int t, int b) {
    const char* Yt = Yb + (size_t)t * 16384;
    char* db = lds + b * 16384;
    #pragma unroll
    for (int s = 0; s < 4; ++s) {
      const int portion = (s * 4 + wave) * 1024;
      const int L = portion + lane * 16;
      const int src = L ^ (((L >> 9) & 15) << 4);
      __builtin_amdgcn_global_load_lds(AS1(Yt + src), AS3(db + portion), 16, 0, 0);
    }
  };

  f32x16 acc[2];
  #pragma unroll
  for (int m = 0; m < 2; ++m)
    #pragma unroll
    for (int r = 0; r < 16; ++r) acc[m][r] = 0.0f;

  stage(0, 0);
  stage(1, 1);
  #pragma unroll 1
  for (int q = 0; q < 4; ++q) {
    const int j = 4 * q;
    // pair A: tiles j, j+1 (bufs 0,1); stage j+2 -> buf2, j+3 -> buf3
    asm volatile("s_waitcnt vmcnt(0)" ::: "memory");
    __builtin_amdgcn_s_barrier();
    stage(j + 2, 2);
    tile_mfma(lds + 0 * 16384, addr0, a, acc, sums);
    stage(j + 3, 3);
    tile_mfma(lds + 1 * 16384, addr0, a, acc, sums);
    // pair B: tiles j+2, j+3 (bufs 2,3); stage j+4 -> buf0, j+5 -> buf1
    asm volatile("s_waitcnt vmcnt(0)" ::: "memory");
    __builtin_amdgcn_s_barrier();
    if (q < 3) stage(j + 4, 0);
    tile_mfma(lds + 2 * 16384, addr0, a, acc, sums);
    if (q < 3) stage(j + 5, 1);
    tile_mfma(lds + 3 * 16384, addr0, a, acc, sums);
  }

  // reduce across the 32 column-lanes; one atomic per row per split.
  // C/D row mapping: row = (g&3) + 8*(g>>2) + 4*lhi, col = l31.
  #pragma unroll
  for (int m = 0; m < 2; ++m)
    #pragma unroll
    for (int g = 0; g < 16; ++g) {
      float s = sums[m][g];
      s += __shfl_xor(s, 1);
      s += __shfl_xor(s, 2);
      s += __shfl_xor(s, 4);
      s += __shfl_xor(s, 8);
      s += __shfl_xor(s, 16);
      if (l31 == 0)
        atomicAdd(row_sum + rowbase + m * 32 + (g & 3) + 8 * (g >> 2) + 4 * lhi, s);
    }
}

// ---------------- loss: single-kernel reduction ----------------
__global__ __launch_bounds__(1024) void loss_kernel(
    const float* __restrict__ row_sum, const float* __restrict__ diag,
    float* __restrict__ out)
{
  const int t = threadIdx.x;
  double acc = 0.0;
  #pragma unroll
  for (int h = 0; h < 2; ++h) {
    const int i = h * 4096 + t * 4;
    const float4 s = *(const float4*)(row_sum + i);
    const float4 d = *(const float4*)(diag + i);
    acc += (double)(kInvT + LOG2F(s.x) * kLn2 - d.x);
    acc += (double)(kInvT + LOG2F(s.y) * kLn2 - d.y);
    acc += (double)(kInvT + LOG2F(s.z) * kLn2 - d.z);
    acc += (double)(kInvT + LOG2F(s.w) * kLn2 - d.w);
  }
  #pragma unroll
  for (int m = 1; m < 64; m <<= 1) acc += __shfl_xor(acc, m);
  __shared__ double red[16];
  if ((t & 63) == 0) red[t >> 6] = acc;
  __syncthreads();
  if (t == 0) {
    double tot = 0.0;
    #pragma unroll
    for (int w = 0; w < 16; ++w) tot += red[w];
    out[0] = (float)(tot / (double)BROWS);
  }
}

extern "C" void kernel_launch(void* const* d_in, const int* in_sizes, int n_in,
                              void* d_out, int out_size, void* d_ws, size_t ws_size,
                              hipStream_t stream) {
  (void)in_sizes; (void)n_in; (void)out_size; (void)ws_size;
  const float* X = (const float*)d_in[0];
  const float* Y = (const float*)d_in[1];
  char* w = (char*)d_ws;
  unsigned short* Xn = (unsigned short*)(w);
  unsigned short* Yn = (unsigned short*)(w + (4u << 20));
  float* diag    = (float*)(w + (8u << 20));
  float* row_sum = (float*)(w + (8u << 20) + (32u << 10));

  nrm_kernel<<<BROWS / 4, 256, 0, stream>>>(X, Y, Xn, Yn, diag, row_sum);
  logits_kernel<<<512, 256, 0, stream>>>(Xn, Yn, row_sum);
  loss_kernel<<<1, 1024, 0, stream>>>(row_sum, diag, (float*)d_out);
}